// Round 2
// baseline (227.390 us; speedup 1.0000x reference)
//
#include <hip/hip_runtime.h>
#include <hip/hip_bf16.h>

#define B_ 16
#define C_ 512
#define N_ 1024
#define KL 256
#define HEADS_ 8
#define DH_ 64

typedef __attribute__((ext_vector_type(8))) short bf16x8;
typedef __attribute__((ext_vector_type(4))) float f32x4;

__device__ inline short f2bf(float f) {
  __hip_bfloat16 h = __float2bfloat16(f);
  return *reinterpret_cast<short*>(&h);
}

__device__ inline void gload16(const void* g, void* l) {
  __builtin_amdgcn_global_load_lds(
      (const __attribute__((address_space(1))) void*)g,
      (__attribute__((address_space(3))) void*)l, 16, 0, 0);
}

// ---------------- GroupNorm: writes xn (f32, [b][c][n]) and xnT (bf16, [b][n][c])
__global__ __launch_bounds__(256) void gn_kernel(
    const float* __restrict__ x, const float* __restrict__ gamma,
    const float* __restrict__ beta, float* __restrict__ xn,
    short* __restrict__ xnT) {
  const int bg = blockIdx.x;
  const int b = bg >> 3;
  const int g = bg & 7;
  const int tid = threadIdx.x;
  const int lane = tid & 63, wid = tid >> 6;

  __shared__ float red[8];
  __shared__ float tile[64 * 65];

  const float* base = x + ((long long)(b * C_ + g * 64)) * N_;
  const float4* b4 = (const float4*)base;
  float s = 0.f, sq = 0.f;
  for (int i = tid; i < 16384; i += 256) {
    float4 v = b4[i];
    s += v.x + v.y + v.z + v.w;
    sq += v.x * v.x + v.y * v.y + v.z * v.z + v.w * v.w;
  }
#pragma unroll
  for (int m = 1; m < 64; m <<= 1) {
    s += __shfl_xor(s, m);
    sq += __shfl_xor(sq, m);
  }
  if (lane == 0) { red[wid] = s; red[4 + wid] = sq; }
  __syncthreads();
  const float ts = red[0] + red[1] + red[2] + red[3];
  const float tq = red[4] + red[5] + red[6] + red[7];
  const float mu = ts * (1.f / 65536.f);
  const float var = tq * (1.f / 65536.f) - mu * mu;
  const float rs = rsqrtf(var + 1e-5f);

  for (int t = 0; t < 16; ++t) {
    const int nT = t * 64;
    for (int idx = tid; idx < 4096; idx += 256) {
      int cl = idx >> 6, nl = idx & 63;
      int ch = g * 64 + cl;
      long long gi = ((long long)(b * C_ + ch)) * N_ + nT + nl;
      float v = (x[gi] - mu) * rs * gamma[ch] + beta[ch];
      xn[gi] = v;
      tile[cl * 65 + nl] = v;
    }
    __syncthreads();
    for (int idx = tid; idx < 4096; idx += 256) {
      int nl = idx >> 6, cl = idx & 63;
      xnT[((long long)b * N_ + nT + nl) * C_ + g * 64 + cl] = f2bf(tile[cl * 65 + nl]);
    }
    __syncthreads();
  }
}

// ---------------- f32 -> bf16 convert
__global__ void conv_bf16_k(const float* __restrict__ src, short* __restrict__ dst, int n) {
  int stride = gridDim.x * blockDim.x;
  for (int i = blockIdx.x * blockDim.x + threadIdx.x; i < n; i += stride)
    dst[i] = f2bf(src[i]);
}

// ---------------- transpose+convert: src [1024][256] f32 -> dst [256][1024] bf16
__global__ __launch_bounds__(256) void tEF(const float* __restrict__ src, short* __restrict__ dst) {
  __shared__ float tl[32 * 33];
  const int bx = blockIdx.x;  // n tile (32)
  const int by = blockIdx.y;  // k tile (8)
  const int lx = threadIdx.x & 31, ly = threadIdx.x >> 5;
#pragma unroll
  for (int i = 0; i < 4; ++i) {
    int n = bx * 32 + ly + i * 8;
    int k = by * 32 + lx;
    tl[(ly + i * 8) * 33 + lx] = src[n * 256 + k];
  }
  __syncthreads();
#pragma unroll
  for (int i = 0; i < 4; ++i) {
    int k = by * 32 + ly + i * 8;
    int n = bx * 32 + lx;
    dst[k * 1024 + n] = f2bf(tl[lx * 33 + (ly + i * 8)]);
  }
}

// ---------------- generic GEMM: C[M][Nn] = A (M x Kd, row-major) * Bt (Nn x Kd, row-major)^T
// BIAS_MODE: 0 none, 1 bias[row], 2 bias[col]. RESID adds f32 resid (same layout as C).
template <int BIAS_MODE, bool OUT_BF16, bool RESID>
__global__ __launch_bounds__(256) void gemm_bt(
    const short* __restrict__ A, const short* __restrict__ Bt,
    void* __restrict__ Cout, const float* __restrict__ bias,
    const float* __restrict__ resid, int M, int Nn, int Kd,
    long long sA, long long sB, long long sC) {
  const int bz = blockIdx.z;
  const int m0 = blockIdx.x * 128;
  const int n0 = blockIdx.y * 128;
  const short* Ab = A + bz * sA;
  const short* Bb = Bt + bz * sB;
  const int tid = threadIdx.x;
  const int lane = tid & 63;
  const int wid = tid >> 6;
  const int wm = wid >> 1, wn = wid & 1;

  __shared__ __align__(16) short As[128 * 64];
  __shared__ __align__(16) short Bs[128 * 64];

  f32x4 acc[4][4] = {};

  for (int kt = 0; kt < Kd; kt += 64) {
#pragma unroll
    for (int r = 0; r < 4; ++r) {
      const int dbase = r * 4096 + wid * 1024;
      const int dbyte = dbase + (lane << 4);
      const int row = dbyte >> 7;
      const int chunk = ((dbyte >> 4) & 7) ^ (row & 7);
      gload16(Ab + (long long)(m0 + row) * Kd + kt + chunk * 8, (char*)As + dbase);
      gload16(Bb + (long long)(n0 + row) * Kd + kt + chunk * 8, (char*)Bs + dbase);
    }
    __syncthreads();
#pragma unroll
    for (int kk = 0; kk < 2; ++kk) {
      bf16x8 af[4], bfr[4];
#pragma unroll
      for (int mi = 0; mi < 4; ++mi) {
        int row = wm * 64 + mi * 16 + (lane & 15);
        int chunk = (kk * 4 + (lane >> 4)) ^ (row & 7);
        af[mi] = *(const bf16x8*)(As + row * 64 + chunk * 8);
      }
#pragma unroll
      for (int ni = 0; ni < 4; ++ni) {
        int row = wn * 64 + ni * 16 + (lane & 15);
        int chunk = (kk * 4 + (lane >> 4)) ^ (row & 7);
        bfr[ni] = *(const bf16x8*)(Bs + row * 64 + chunk * 8);
      }
#pragma unroll
      for (int mi = 0; mi < 4; ++mi)
#pragma unroll
        for (int ni = 0; ni < 4; ++ni)
          acc[mi][ni] = __builtin_amdgcn_mfma_f32_16x16x32_bf16(af[mi], bfr[ni], acc[mi][ni], 0, 0, 0);
    }
    __syncthreads();
  }

#pragma unroll
  for (int mi = 0; mi < 4; ++mi) {
#pragma unroll
    for (int ni = 0; ni < 4; ++ni) {
      const int row = m0 + wm * 64 + mi * 16 + ((lane >> 4) << 2);
      const int col = n0 + wn * 64 + ni * 16 + (lane & 15);
      f32x4 v = acc[mi][ni];
#pragma unroll
      for (int j = 0; j < 4; ++j) {
        float val = v[j];
        if (BIAS_MODE == 1) val += bias[row + j];
        if (BIAS_MODE == 2) val += bias[col];
        long long ci = bz * sC + (long long)(row + j) * Nn + col;
        if (RESID) val += resid[ci];
        if (OUT_BF16)
          ((short*)Cout)[ci] = f2bf(val);
        else
          ((float*)Cout)[ci] = val;
      }
    }
  }
}

// ---------------- fused Linformer attention
// q: [b][n][512] bf16; kp: [b][256][512] bf16; vp: [b][512][256] bf16; o: [b][n][512] bf16
__global__ __launch_bounds__(256) void attn_fused(
    const short* __restrict__ q, const short* __restrict__ kp,
    const short* __restrict__ vp, short* __restrict__ o) {
  const int nb = blockIdx.x;
  const int h = blockIdx.y;
  const int b = blockIdx.z;
  const int tid = threadIdx.x;
  const int lane = tid & 63;
  const int wid = tid >> 6;

  __shared__ __align__(16) short buf[256 * 64];      // 32KB: kp tile, then vpT tile
  __shared__ __align__(16) short plds[4][4096];      // 32KB: per-wave P tiles

  // stage kp tile [256 rows(k)][64 cols(d)], swizzled (8 chunks/row)
  {
    const short* base = kp + (long long)b * (KL * C_) + h * DH_;
#pragma unroll
    for (int r = 0; r < 8; ++r) {
      const int dbase = r * 4096 + wid * 1024;
      const int dbyte = dbase + (lane << 4);
      const int row = dbyte >> 7;
      const int chunk = ((dbyte >> 4) & 7) ^ (row & 7);
      gload16(base + row * C_ + chunk * 8, (char*)buf + dbase);
    }
  }
  __syncthreads();

  // q fragments: rows n = nb*64 + wid*16 + (lane&15), k = d
  bf16x8 aq[2];
  {
    const short* qb = q + ((long long)b * N_ + nb * 64 + wid * 16 + (lane & 15)) * C_ +
                      h * DH_ + ((lane >> 4) << 3);
    aq[0] = *(const bf16x8*)qb;
    aq[1] = *(const bf16x8*)(qb + 32);
  }

  // scores: 16 rows x 256 cols per wave
  f32x4 sc[16];
#pragma unroll
  for (int kc = 0; kc < 16; ++kc) {
    f32x4 a = {0.f, 0.f, 0.f, 0.f};
#pragma unroll
    for (int kk = 0; kk < 2; ++kk) {
      int row = kc * 16 + (lane & 15);
      int chunk = (kk * 4 + (lane >> 4)) ^ (row & 7);
      bf16x8 bk = *(const bf16x8*)(buf + row * 64 + chunk * 8);
      a = __builtin_amdgcn_mfma_f32_16x16x32_bf16(aq[kk], bk, a, 0, 0, 0);
    }
    sc[kc] = a * 0.125f;  // 1/sqrt(64)
  }

  // softmax over 256 cols; row r=(lane>>4)*4+j lives in the 16 lanes sharing lane>>4
  float inv[4];
#pragma unroll
  for (int j = 0; j < 4; ++j) {
    float m = -1e30f;
#pragma unroll
    for (int kc = 0; kc < 16; ++kc) m = fmaxf(m, sc[kc][j]);
    m = fmaxf(m, __shfl_xor(m, 1));
    m = fmaxf(m, __shfl_xor(m, 2));
    m = fmaxf(m, __shfl_xor(m, 4));
    m = fmaxf(m, __shfl_xor(m, 8));
    float s = 0.f;
#pragma unroll
    for (int kc = 0; kc < 16; ++kc) {
      float p = __expf(sc[kc][j] - m);
      sc[kc][j] = p;
      s += p;
    }
    s += __shfl_xor(s, 1);
    s += __shfl_xor(s, 2);
    s += __shfl_xor(s, 4);
    s += __shfl_xor(s, 8);
    inv[j] = 1.f / s;
  }

  // write P (bf16) to per-wave LDS tile [16][256], swizzled on element bits 3..5
#pragma unroll
  for (int kc = 0; kc < 16; ++kc) {
#pragma unroll
    for (int j = 0; j < 4; ++j) {
      int rrow = ((lane >> 4) << 2) + j;
      int col = kc * 16 + (lane & 15);
      plds[wid][rrow * 256 + (col ^ ((rrow & 7) << 3))] = f2bf(sc[kc][j]);
    }
  }

  __syncthreads();  // all waves done reading kp tile

  // stage vpT tile [64 rows(d)][256 cols(k)], swizzled (32 chunks/row, XOR low 3 bits)
  {
    const short* base = vp + (long long)b * (C_ * KL) + h * DH_ * KL;
#pragma unroll
    for (int r = 0; r < 8; ++r) {
      const int dbase = r * 4096 + wid * 1024;
      const int dbyte = dbase + (lane << 4);
      const int row = dbyte >> 9;
      const int chunk = ((dbyte >> 4) & 31) ^ (row & 7);
      gload16(base + row * KL + chunk * 8, (char*)buf + dbase);
    }
  }
  __syncthreads();

  // PV: out[n][d] = sum_k P[n][k] * vpT[d][k]
#pragma unroll
  for (int dt = 0; dt < 4; ++dt) {
    f32x4 ao = {0.f, 0.f, 0.f, 0.f};
#pragma unroll
    for (int kk = 0; kk < 8; ++kk) {
      int prow = lane & 15;
      bf16x8 ap = *(const bf16x8*)(&plds[wid][prow * 256 +
                   ((kk * 32 + ((lane >> 4) << 3)) ^ ((prow & 7) << 3))]);
      int vrow = dt * 16 + (lane & 15);
      int chunk = (kk * 4 + (lane >> 4)) ^ (vrow & 7);
      bf16x8 bv = *(const bf16x8*)(buf + vrow * 256 + chunk * 8);
      ao = __builtin_amdgcn_mfma_f32_16x16x32_bf16(ap, bv, ao, 0, 0, 0);
    }
#pragma unroll
    for (int j = 0; j < 4; ++j) {
      int n = nb * 64 + wid * 16 + ((lane >> 4) << 2) + j;
      int d = dt * 16 + (lane & 15);
      o[((long long)b * N_ + n) * C_ + h * DH_ + d] = f2bf(ao[j] * inv[j]);
    }
  }
}

extern "C" void kernel_launch(void* const* d_in, const int* in_sizes, int n_in,
                              void* d_out, int out_size, void* d_ws, size_t ws_size,
                              hipStream_t stream) {
  (void)in_sizes; (void)n_in; (void)out_size; (void)ws_size;
  const float* x      = (const float*)d_in[0];
  const float* gamma  = (const float*)d_in[1];
  const float* beta   = (const float*)d_in[2];
  const float* w_qkv  = (const float*)d_in[3];
  const float* b_qkv  = (const float*)d_in[4];
  const float* E      = (const float*)d_in[5];
  const float* F      = (const float*)d_in[6];
  const float* w_o    = (const float*)d_in[7];
  const float* b_o    = (const float*)d_in[8];
  const float* w_proj = (const float*)d_in[9];
  const float* b_proj = (const float*)d_in[10];
  float* out = (float*)d_out;

  // Workspace layout with liveness-based aliasing (~108 MB total):
  //   xnT dead after S1b -> attno reuses it.
  //   kvbuf dead after S2b -> ybuf reuses it.
  char* ws = (char*)d_ws;
  float* xn     = (float*)ws;  ws += 33554432LL;   // [16][512][1024] f32
  short* xnT    = (short*)ws;  ws += 16777216LL;   // [16][1024][512] bf16 (later: attno)
  short* qbuf   = (short*)ws;  ws += 16777216LL;   // [16][1024][512] bf16
  short* kvbuf  = (short*)ws;  ws += 33554432LL;   // [16][1024][1024] bf16 (later: ybuf)
  short* kpb    = (short*)ws;  ws += 4194304LL;    // [16][256][512] bf16
  short* vpb    = (short*)ws;  ws += 4194304LL;    // [16][512][256] bf16
  short* wqkv_b = (short*)ws;  ws += 1572864LL;    // [1536][512] bf16
  short* wo_b   = (short*)ws;  ws += 524288LL;     // [512][512] bf16
  short* wproj_b= (short*)ws;  ws += 524288LL;     // [512][512] bf16
  short* Et     = (short*)ws;  ws += 524288LL;     // [256][1024] bf16
  short* Ft     = (short*)ws;  ws += 524288LL;     // [256][1024] bf16
  short* attno  = xnT;                             // alias: [16][1024][512] bf16
  short* ybuf   = kvbuf;                           // alias: [16][1024][512] bf16

  // GroupNorm
  gn_kernel<<<dim3(128), dim3(256), 0, stream>>>(x, gamma, beta, xn, xnT);
  // weight prep
  conv_bf16_k<<<dim3(512), dim3(256), 0, stream>>>(w_qkv, wqkv_b, 786432);
  conv_bf16_k<<<dim3(256), dim3(256), 0, stream>>>(w_o, wo_b, 262144);
  conv_bf16_k<<<dim3(256), dim3(256), 0, stream>>>(w_proj, wproj_b, 262144);
  tEF<<<dim3(32, 8), dim3(256), 0, stream>>>(E, Et);
  tEF<<<dim3(32, 8), dim3(256), 0, stream>>>(F, Ft);

  // S1a: q[b][n][o] = xnT[b] (1024x512) * w_q^T + b_qkv[col]
  gemm_bt<2, true, false><<<dim3(8, 4, 16), dim3(256), 0, stream>>>(
      xnT, wqkv_b, qbuf, b_qkv, nullptr, 1024, 512, 512,
      1024LL * 512, 0, 1024LL * 512);
  // S1b: kv[b][o'][n] = w_kv (1024x512) * xnT[b]^T + b_qkv[512+row]
  gemm_bt<1, true, false><<<dim3(8, 8, 16), dim3(256), 0, stream>>>(
      wqkv_b + 512 * 512, xnT, kvbuf, b_qkv + 512, nullptr, 1024, 1024, 512,
      0, 1024LL * 512, 1024LL * 1024);
  // S2a: kp[b][k][c] = Et (256x1024) * k_cn[b]^T
  gemm_bt<0, true, false><<<dim3(2, 4, 16), dim3(256), 0, stream>>>(
      Et, kvbuf, kpb, nullptr, nullptr, 256, 512, 1024,
      0, 1024LL * 1024, 256LL * 512);
  // S2b: vp[b][c][k] = v_cn[b] (512x1024) * Ft^T
  gemm_bt<0, true, false><<<dim3(4, 2, 16), dim3(256), 0, stream>>>(
      kvbuf + 512 * 1024, Ft, vpb, nullptr, nullptr, 512, 256, 1024,
      1024LL * 1024, 0, 512LL * 256);
  // attention
  attn_fused<<<dim3(16, 8, 16), dim3(256), 0, stream>>>(qbuf, kpb, vpb, attno);
  // S4: y[b][n][o] = attno[b] (1024x512) * w_o^T + b_o[col]
  gemm_bt<2, true, false><<<dim3(8, 4, 16), dim3(256), 0, stream>>>(
      attno, wo_b, ybuf, b_o, nullptr, 1024, 512, 512,
      1024LL * 512, 0, 1024LL * 512);
  // S5: out[b][o][n] = w_proj (512x512) * y[b]^T + b_proj[row] + xn
  gemm_bt<1, false, true><<<dim3(4, 8, 16), dim3(256), 0, stream>>>(
      wproj_b, ybuf, out, b_proj, xn, 512, 1024, 512,
      0, 1024LL * 512, 512LL * 1024);
}

// Round 3
// 182.731 us; speedup vs baseline: 1.2444x; 1.2444x over previous
//
#include <hip/hip_runtime.h>
#include <hip/hip_bf16.h>

#define B_ 16
#define C_ 512
#define N_ 1024
#define KL 256
#define HEADS_ 8
#define DH_ 64

typedef __attribute__((ext_vector_type(8))) short bf16x8;
typedef __attribute__((ext_vector_type(4))) float f32x4;

__device__ inline short f2bf(float f) {
  __hip_bfloat16 h = __float2bfloat16(f);
  return *reinterpret_cast<short*>(&h);
}

__device__ inline float bf2f(short s) {
  union { unsigned int u; float f; } c;
  c.u = ((unsigned int)(unsigned short)s) << 16;
  return c.f;
}

__device__ inline void gload16(const void* g, void* l) {
  __builtin_amdgcn_global_load_lds(
      (const __attribute__((address_space(1))) void*)g,
      (__attribute__((address_space(3))) void*)l, 16, 0, 0);
}

// ---------------- GroupNorm stats pass 1: 1024 blocks = (b,g) x 8 slices of 8192 elems
__global__ __launch_bounds__(256) void gn_stats1(const float* __restrict__ x,
                                                 float2* __restrict__ part) {
  const int tid = threadIdx.x;
  const int lane = tid & 63, wid = tid >> 6;
  const float4* b4 = (const float4*)(x + (long long)blockIdx.x * 8192);
  float s = 0.f, sq = 0.f;
#pragma unroll
  for (int j = 0; j < 8; ++j) {
    float4 v = b4[tid + j * 256];
    s += v.x + v.y + v.z + v.w;
    sq += v.x * v.x + v.y * v.y + v.z * v.z + v.w * v.w;
  }
#pragma unroll
  for (int m = 1; m < 64; m <<= 1) {
    s += __shfl_xor(s, m);
    sq += __shfl_xor(sq, m);
  }
  __shared__ float red[8];
  if (lane == 0) { red[wid] = s; red[4 + wid] = sq; }
  __syncthreads();
  if (tid == 0)
    part[blockIdx.x] = make_float2(red[0] + red[1] + red[2] + red[3],
                                   red[4] + red[5] + red[6] + red[7]);
}

// ---------------- GroupNorm stats finalize: 1 block, 128 threads (one per (b,g))
__global__ void gn_stats2(const float2* __restrict__ part, float2* __restrict__ musd) {
  const int i = threadIdx.x;
  if (i < 128) {
    float s = 0.f, sq = 0.f;
#pragma unroll
    for (int j = 0; j < 8; ++j) {
      float2 p = part[i * 8 + j];
      s += p.x; sq += p.y;
    }
    const float mu = s * (1.f / 65536.f);
    const float var = sq * (1.f / 65536.f) - mu * mu;
    musd[i] = make_float2(mu, rsqrtf(var + 1e-5f));
  }
}

// ---------------- GroupNorm apply: 2048 blocks = (ntile 16, g 8, b 16); 64c x 64n tile
// writes xnc (bf16 [b][c][n]) and xnT (bf16 [b][n][c])
__global__ __launch_bounds__(256) void gn_apply(
    const float* __restrict__ x, const float* __restrict__ gamma,
    const float* __restrict__ beta, const float2* __restrict__ musd,
    short* __restrict__ xnc, short* __restrict__ xnT) {
  const int t = blockIdx.x, g = blockIdx.y, b = blockIdx.z;
  const float2 ms = musd[b * 8 + g];
  __shared__ short tile[64 * 65];

  // read + normalize + write xnc (vectorized), stash bf16 in LDS
#pragma unroll
  for (int i = 0; i < 4; ++i) {
    const int idx = threadIdx.x + i * 256;   // 0..1023 float4-units
    const int cl = idx >> 4;                 // channel-in-group
    const int nl0 = (idx & 15) * 4;          // n-offset in tile
    const int ch = g * 64 + cl;
    const long long gi = ((long long)(b * C_ + ch)) * N_ + t * 64 + nl0;
    const float4 v = *(const float4*)(x + gi);
    const float gm = gamma[ch], bt = beta[ch];
    short s0 = f2bf((v.x - ms.x) * ms.y * gm + bt);
    short s1 = f2bf((v.y - ms.x) * ms.y * gm + bt);
    short s2 = f2bf((v.z - ms.x) * ms.y * gm + bt);
    short s3 = f2bf((v.w - ms.x) * ms.y * gm + bt);
    short4 pk; pk.x = s0; pk.y = s1; pk.z = s2; pk.w = s3;
    *(short4*)(xnc + gi) = pk;
    tile[cl * 65 + nl0] = s0;
    tile[cl * 65 + nl0 + 1] = s1;
    tile[cl * 65 + nl0 + 2] = s2;
    tile[cl * 65 + nl0 + 3] = s3;
  }
  __syncthreads();

  // transposed write: 4 consecutive channels per thread -> short4
#pragma unroll
  for (int i = 0; i < 4; ++i) {
    const int idx = threadIdx.x + i * 256;   // 0..1023 short4-units
    const int cl0 = (idx & 15) * 4;
    const int nl = idx >> 4;
    short4 pk;
    pk.x = tile[(cl0 + 0) * 65 + nl];
    pk.y = tile[(cl0 + 1) * 65 + nl];
    pk.z = tile[(cl0 + 2) * 65 + nl];
    pk.w = tile[(cl0 + 3) * 65 + nl];
    *(short4*)(xnT + ((long long)b * N_ + t * 64 + nl) * C_ + g * 64 + cl0) = pk;
  }
}

// ---------------- f32 -> bf16 convert
__global__ void conv_bf16_k(const float* __restrict__ src, short* __restrict__ dst, int n) {
  int stride = gridDim.x * blockDim.x;
  for (int i = blockIdx.x * blockDim.x + threadIdx.x; i < n; i += stride)
    dst[i] = f2bf(src[i]);
}

// ---------------- transpose+convert: src [1024][256] f32 -> dst [256][1024] bf16
__global__ __launch_bounds__(256) void tEF(const float* __restrict__ src, short* __restrict__ dst) {
  __shared__ float tl[32 * 33];
  const int bx = blockIdx.x;  // n tile (32)
  const int by = blockIdx.y;  // k tile (8)
  const int lx = threadIdx.x & 31, ly = threadIdx.x >> 5;
#pragma unroll
  for (int i = 0; i < 4; ++i) {
    int n = bx * 32 + ly + i * 8;
    int k = by * 32 + lx;
    tl[(ly + i * 8) * 33 + lx] = src[n * 256 + k];
  }
  __syncthreads();
#pragma unroll
  for (int i = 0; i < 4; ++i) {
    int k = by * 32 + ly + i * 8;
    int n = bx * 32 + lx;
    dst[k * 1024 + n] = f2bf(tl[lx * 33 + (ly + i * 8)]);
  }
}

// ---------------- generic GEMM: C[M][Nn] = A (M x Kd, row-major) * Bt (Nn x Kd, row-major)^T
// BIAS_MODE: 0 none, 1 bias[row], 2 bias[col]. RESID adds bf16 resid (same layout as C).
template <int BIAS_MODE, bool OUT_BF16, bool RESID>
__global__ __launch_bounds__(256) void gemm_bt(
    const short* __restrict__ A, const short* __restrict__ Bt,
    void* __restrict__ Cout, const float* __restrict__ bias,
    const short* __restrict__ resid, int M, int Nn, int Kd,
    long long sA, long long sB, long long sC) {
  const int bz = blockIdx.z;
  const int m0 = blockIdx.x * 128;
  const int n0 = blockIdx.y * 128;
  const short* Ab = A + bz * sA;
  const short* Bb = Bt + bz * sB;
  const int tid = threadIdx.x;
  const int lane = tid & 63;
  const int wid = tid >> 6;
  const int wm = wid >> 1, wn = wid & 1;

  __shared__ __align__(16) short As[128 * 64];
  __shared__ __align__(16) short Bs[128 * 64];

  f32x4 acc[4][4] = {};

  for (int kt = 0; kt < Kd; kt += 64) {
#pragma unroll
    for (int r = 0; r < 4; ++r) {
      const int dbase = r * 4096 + wid * 1024;
      const int dbyte = dbase + (lane << 4);
      const int row = dbyte >> 7;
      const int chunk = ((dbyte >> 4) & 7) ^ (row & 7);
      gload16(Ab + (long long)(m0 + row) * Kd + kt + chunk * 8, (char*)As + dbase);
      gload16(Bb + (long long)(n0 + row) * Kd + kt + chunk * 8, (char*)Bs + dbase);
    }
    __syncthreads();
#pragma unroll
    for (int kk = 0; kk < 2; ++kk) {
      bf16x8 af[4], bfr[4];
#pragma unroll
      for (int mi = 0; mi < 4; ++mi) {
        int row = wm * 64 + mi * 16 + (lane & 15);
        int chunk = (kk * 4 + (lane >> 4)) ^ (row & 7);
        af[mi] = *(const bf16x8*)(As + row * 64 + chunk * 8);
      }
#pragma unroll
      for (int ni = 0; ni < 4; ++ni) {
        int row = wn * 64 + ni * 16 + (lane & 15);
        int chunk = (kk * 4 + (lane >> 4)) ^ (row & 7);
        bfr[ni] = *(const bf16x8*)(Bs + row * 64 + chunk * 8);
      }
#pragma unroll
      for (int mi = 0; mi < 4; ++mi)
#pragma unroll
        for (int ni = 0; ni < 4; ++ni)
          acc[mi][ni] = __builtin_amdgcn_mfma_f32_16x16x32_bf16(af[mi], bfr[ni], acc[mi][ni], 0, 0, 0);
    }
    __syncthreads();
  }

#pragma unroll
  for (int mi = 0; mi < 4; ++mi) {
#pragma unroll
    for (int ni = 0; ni < 4; ++ni) {
      const int row = m0 + wm * 64 + mi * 16 + ((lane >> 4) << 2);
      const int col = n0 + wn * 64 + ni * 16 + (lane & 15);
      f32x4 v = acc[mi][ni];
#pragma unroll
      for (int j = 0; j < 4; ++j) {
        float val = v[j];
        if (BIAS_MODE == 1) val += bias[row + j];
        if (BIAS_MODE == 2) val += bias[col];
        long long ci = bz * sC + (long long)(row + j) * Nn + col;
        if (RESID) val += bf2f(resid[ci]);
        if (OUT_BF16)
          ((short*)Cout)[ci] = f2bf(val);
        else
          ((float*)Cout)[ci] = val;
      }
    }
  }
}

// ---------------- fused Linformer attention
// q: [b][n][512] bf16; kp: [b][256][512] bf16; vp: [b][512][256] bf16; o: [b][n][512] bf16
__global__ __launch_bounds__(256) void attn_fused(
    const short* __restrict__ q, const short* __restrict__ kp,
    const short* __restrict__ vp, short* __restrict__ o) {
  const int nb = blockIdx.x;
  const int h = blockIdx.y;
  const int b = blockIdx.z;
  const int tid = threadIdx.x;
  const int lane = tid & 63;
  const int wid = tid >> 6;

  __shared__ __align__(16) short buf[256 * 64];      // 32KB: kp tile, then vpT tile
  __shared__ __align__(16) short plds[4][4096];      // 32KB: per-wave P tiles

  // stage kp tile [256 rows(k)][64 cols(d)], swizzled (8 chunks/row)
  {
    const short* base = kp + (long long)b * (KL * C_) + h * DH_;
#pragma unroll
    for (int r = 0; r < 8; ++r) {
      const int dbase = r * 4096 + wid * 1024;
      const int dbyte = dbase + (lane << 4);
      const int row = dbyte >> 7;
      const int chunk = ((dbyte >> 4) & 7) ^ (row & 7);
      gload16(base + row * C_ + chunk * 8, (char*)buf + dbase);
    }
  }
  __syncthreads();

  // q fragments: rows n = nb*64 + wid*16 + (lane&15), k = d
  bf16x8 aq[2];
  {
    const short* qb = q + ((long long)b * N_ + nb * 64 + wid * 16 + (lane & 15)) * C_ +
                      h * DH_ + ((lane >> 4) << 3);
    aq[0] = *(const bf16x8*)qb;
    aq[1] = *(const bf16x8*)(qb + 32);
  }

  // scores: 16 rows x 256 cols per wave
  f32x4 sc[16];
#pragma unroll
  for (int kc = 0; kc < 16; ++kc) {
    f32x4 a = {0.f, 0.f, 0.f, 0.f};
#pragma unroll
    for (int kk = 0; kk < 2; ++kk) {
      int row = kc * 16 + (lane & 15);
      int chunk = (kk * 4 + (lane >> 4)) ^ (row & 7);
      bf16x8 bk = *(const bf16x8*)(buf + row * 64 + chunk * 8);
      a = __builtin_amdgcn_mfma_f32_16x16x32_bf16(aq[kk], bk, a, 0, 0, 0);
    }
    sc[kc] = a * 0.125f;  // 1/sqrt(64)
  }

  // softmax over 256 cols; row r=(lane>>4)*4+j lives in the 16 lanes sharing lane>>4
  float inv[4];
#pragma unroll
  for (int j = 0; j < 4; ++j) {
    float m = -1e30f;
#pragma unroll
    for (int kc = 0; kc < 16; ++kc) m = fmaxf(m, sc[kc][j]);
    m = fmaxf(m, __shfl_xor(m, 1));
    m = fmaxf(m, __shfl_xor(m, 2));
    m = fmaxf(m, __shfl_xor(m, 4));
    m = fmaxf(m, __shfl_xor(m, 8));
    float s = 0.f;
#pragma unroll
    for (int kc = 0; kc < 16; ++kc) {
      float p = __expf(sc[kc][j] - m);
      sc[kc][j] = p;
      s += p;
    }
    s += __shfl_xor(s, 1);
    s += __shfl_xor(s, 2);
    s += __shfl_xor(s, 4);
    s += __shfl_xor(s, 8);
    inv[j] = 1.f / s;
  }

  // write P (bf16) to per-wave LDS tile [16][256], swizzled on element bits 3..5
#pragma unroll
  for (int kc = 0; kc < 16; ++kc) {
#pragma unroll
    for (int j = 0; j < 4; ++j) {
      int rrow = ((lane >> 4) << 2) + j;
      int col = kc * 16 + (lane & 15);
      plds[wid][rrow * 256 + (col ^ ((rrow & 7) << 3))] = f2bf(sc[kc][j]);
    }
  }

  __syncthreads();  // all waves done reading kp tile

  // stage vpT tile [64 rows(d)][256 cols(k)], swizzled (32 chunks/row, XOR low 3 bits)
  {
    const short* base = vp + (long long)b * (C_ * KL) + h * DH_ * KL;
#pragma unroll
    for (int r = 0; r < 8; ++r) {
      const int dbase = r * 4096 + wid * 1024;
      const int dbyte = dbase + (lane << 4);
      const int row = dbyte >> 9;
      const int chunk = ((dbyte >> 4) & 31) ^ (row & 7);
      gload16(base + row * KL + chunk * 8, (char*)buf + dbase);
    }
  }
  __syncthreads();

  // PV: out[n][d] = sum_k P[n][k] * vpT[d][k]
#pragma unroll
  for (int dt = 0; dt < 4; ++dt) {
    f32x4 ao = {0.f, 0.f, 0.f, 0.f};
#pragma unroll
    for (int kk = 0; kk < 8; ++kk) {
      int prow = lane & 15;
      bf16x8 ap = *(const bf16x8*)(&plds[wid][prow * 256 +
                   ((kk * 32 + ((lane >> 4) << 3)) ^ ((prow & 7) << 3))]);
      int vrow = dt * 16 + (lane & 15);
      int chunk = (kk * 4 + (lane >> 4)) ^ (vrow & 7);
      bf16x8 bv = *(const bf16x8*)(buf + vrow * 256 + chunk * 8);
      ao = __builtin_amdgcn_mfma_f32_16x16x32_bf16(ap, bv, ao, 0, 0, 0);
    }
#pragma unroll
    for (int j = 0; j < 4; ++j) {
      int n = nb * 64 + wid * 16 + ((lane >> 4) << 2) + j;
      int d = dt * 16 + (lane & 15);
      o[((long long)b * N_ + n) * C_ + h * DH_ + d] = f2bf(ao[j] * inv[j]);
    }
  }
}

extern "C" void kernel_launch(void* const* d_in, const int* in_sizes, int n_in,
                              void* d_out, int out_size, void* d_ws, size_t ws_size,
                              hipStream_t stream) {
  (void)in_sizes; (void)n_in; (void)out_size; (void)ws_size;
  const float* x      = (const float*)d_in[0];
  const float* gamma  = (const float*)d_in[1];
  const float* beta   = (const float*)d_in[2];
  const float* w_qkv  = (const float*)d_in[3];
  const float* b_qkv  = (const float*)d_in[4];
  const float* E      = (const float*)d_in[5];
  const float* F      = (const float*)d_in[6];
  const float* w_o    = (const float*)d_in[7];
  const float* b_o    = (const float*)d_in[8];
  const float* w_proj = (const float*)d_in[9];
  const float* b_proj = (const float*)d_in[10];
  float* out = (float*)d_out;

  // Workspace layout with liveness-based aliasing:
  //   xnT dead after S1b -> attno reuses it.
  //   kvbuf dead after S2b -> ybuf reuses it.
  char* ws = (char*)d_ws;
  short* xnc    = (short*)ws;  ws += 16777216LL;   // [16][512][1024] bf16 (residual)
  short* xnT    = (short*)ws;  ws += 16777216LL;   // [16][1024][512] bf16 (later: attno)
  short* qbuf   = (short*)ws;  ws += 16777216LL;   // [16][1024][512] bf16
  short* kvbuf  = (short*)ws;  ws += 33554432LL;   // [16][1024][1024] bf16 (later: ybuf)
  short* kpb    = (short*)ws;  ws += 4194304LL;    // [16][256][512] bf16
  short* vpb    = (short*)ws;  ws += 4194304LL;    // [16][512][256] bf16
  short* wqkv_b = (short*)ws;  ws += 1572864LL;    // [1536][512] bf16
  short* wo_b   = (short*)ws;  ws += 524288LL;     // [512][512] bf16
  short* wproj_b= (short*)ws;  ws += 524288LL;     // [512][512] bf16
  short* Et     = (short*)ws;  ws += 524288LL;     // [256][1024] bf16
  short* Ft     = (short*)ws;  ws += 524288LL;     // [256][1024] bf16
  float2* part  = (float2*)ws; ws += 8192LL;       // [1024] partial (sum, sumsq)
  float2* musd  = (float2*)ws; ws += 1024LL;       // [128] (mu, rs)
  short* attno  = xnT;                             // alias: [16][1024][512] bf16
  short* ybuf   = kvbuf;                           // alias: [16][1024][512] bf16

  // GroupNorm (3 stages, fully parallel)
  gn_stats1<<<dim3(1024), dim3(256), 0, stream>>>(x, part);
  gn_stats2<<<dim3(1), dim3(128), 0, stream>>>(part, musd);
  gn_apply<<<dim3(16, 8, 16), dim3(256), 0, stream>>>(x, gamma, beta, musd, xnc, xnT);

  // weight prep
  conv_bf16_k<<<dim3(512), dim3(256), 0, stream>>>(w_qkv, wqkv_b, 786432);
  conv_bf16_k<<<dim3(256), dim3(256), 0, stream>>>(w_o, wo_b, 262144);
  conv_bf16_k<<<dim3(256), dim3(256), 0, stream>>>(w_proj, wproj_b, 262144);
  tEF<<<dim3(32, 8), dim3(256), 0, stream>>>(E, Et);
  tEF<<<dim3(32, 8), dim3(256), 0, stream>>>(F, Ft);

  // S1a: q[b][n][o] = xnT[b] (1024x512) * w_q^T + b_qkv[col]
  gemm_bt<2, true, false><<<dim3(8, 4, 16), dim3(256), 0, stream>>>(
      xnT, wqkv_b, qbuf, b_qkv, nullptr, 1024, 512, 512,
      1024LL * 512, 0, 1024LL * 512);
  // S1b: kv[b][o'][n] = w_kv (1024x512) * xnT[b]^T + b_qkv[512+row]
  gemm_bt<1, true, false><<<dim3(8, 8, 16), dim3(256), 0, stream>>>(
      wqkv_b + 512 * 512, xnT, kvbuf, b_qkv + 512, nullptr, 1024, 1024, 512,
      0, 1024LL * 512, 1024LL * 1024);
  // S2a: kp[b][k][c] = Et (256x1024) * k_cn[b]^T
  gemm_bt<0, true, false><<<dim3(2, 4, 16), dim3(256), 0, stream>>>(
      Et, kvbuf, kpb, nullptr, nullptr, 256, 512, 1024,
      0, 1024LL * 1024, 256LL * 512);
  // S2b: vp[b][c][k] = v_cn[b] (512x1024) * Ft^T
  gemm_bt<0, true, false><<<dim3(4, 2, 16), dim3(256), 0, stream>>>(
      kvbuf + 512 * 1024, Ft, vpb, nullptr, nullptr, 512, 256, 1024,
      1024LL * 1024, 0, 512LL * 256);
  // attention
  attn_fused<<<dim3(16, 8, 16), dim3(256), 0, stream>>>(qbuf, kpb, vpb, attno);
  // S4: y[b][n][o] = attno[b] (1024x512) * w_o^T + b_o[col]
  gemm_bt<2, true, false><<<dim3(8, 4, 16), dim3(256), 0, stream>>>(
      attno, wo_b, ybuf, b_o, nullptr, 1024, 512, 512,
      1024LL * 512, 0, 1024LL * 512);
  // S5: out[b][o][n] = w_proj (512x512) * y[b]^T + b_proj[row] + xnc (bf16 resid)
  gemm_bt<1, false, true><<<dim3(4, 8, 16), dim3(256), 0, stream>>>(
      wproj_b, ybuf, out, b_proj, xnc, 512, 1024, 512,
      0, 1024LL * 512, 512LL * 1024);
}

// Round 4
// 176.677 us; speedup vs baseline: 1.2870x; 1.0343x over previous
//
#include <hip/hip_runtime.h>
#include <hip/hip_bf16.h>

#define B_ 16
#define C_ 512
#define N_ 1024
#define KL 256
#define HEADS_ 8
#define DH_ 64

typedef __attribute__((ext_vector_type(8))) short bf16x8;
typedef __attribute__((ext_vector_type(4))) float f32x4;
typedef __attribute__((ext_vector_type(16))) float f32x16;

__device__ inline short f2bf(float f) {
  __hip_bfloat16 h = __float2bfloat16(f);
  return *reinterpret_cast<short*>(&h);
}

__device__ inline float bf2f(short s) {
  union { unsigned int u; float f; } c;
  c.u = ((unsigned int)(unsigned short)s) << 16;
  return c.f;
}

__device__ inline void gload16(const void* g, void* l) {
  __builtin_amdgcn_global_load_lds(
      (const __attribute__((address_space(1))) void*)g,
      (__attribute__((address_space(3))) void*)l, 16, 0, 0);
}

// ---------------- GroupNorm stats pass 1: 1024 blocks = (b,g) x 8 slices of 8192 elems
__global__ __launch_bounds__(256) void gn_stats1(const float* __restrict__ x,
                                                 float2* __restrict__ part) {
  const int tid = threadIdx.x;
  const int lane = tid & 63, wid = tid >> 6;
  const float4* b4 = (const float4*)(x + (long long)blockIdx.x * 8192);
  float s = 0.f, sq = 0.f;
#pragma unroll
  for (int j = 0; j < 8; ++j) {
    float4 v = b4[tid + j * 256];
    s += v.x + v.y + v.z + v.w;
    sq += v.x * v.x + v.y * v.y + v.z * v.z + v.w * v.w;
  }
#pragma unroll
  for (int m = 1; m < 64; m <<= 1) {
    s += __shfl_xor(s, m);
    sq += __shfl_xor(sq, m);
  }
  __shared__ float red[8];
  if (lane == 0) { red[wid] = s; red[4 + wid] = sq; }
  __syncthreads();
  if (tid == 0)
    part[blockIdx.x] = make_float2(red[0] + red[1] + red[2] + red[3],
                                   red[4] + red[5] + red[6] + red[7]);
}

// ---------------- GroupNorm stats finalize
__global__ void gn_stats2(const float2* __restrict__ part, float2* __restrict__ musd) {
  const int i = threadIdx.x;
  if (i < 128) {
    float s = 0.f, sq = 0.f;
#pragma unroll
    for (int j = 0; j < 8; ++j) {
      float2 p = part[i * 8 + j];
      s += p.x; sq += p.y;
    }
    const float mu = s * (1.f / 65536.f);
    const float var = sq * (1.f / 65536.f) - mu * mu;
    musd[i] = make_float2(mu, rsqrtf(var + 1e-5f));
  }
}

// ---------------- GroupNorm apply: writes xnc (bf16 [b][c][n]) and xnT (bf16 [b][n][c])
__global__ __launch_bounds__(256) void gn_apply(
    const float* __restrict__ x, const float* __restrict__ gamma,
    const float* __restrict__ beta, const float2* __restrict__ musd,
    short* __restrict__ xnc, short* __restrict__ xnT) {
  const int t = blockIdx.x, g = blockIdx.y, b = blockIdx.z;
  const float2 ms = musd[b * 8 + g];
  __shared__ short tile[64 * 65];

#pragma unroll
  for (int i = 0; i < 4; ++i) {
    const int idx = threadIdx.x + i * 256;
    const int cl = idx >> 4;
    const int nl0 = (idx & 15) * 4;
    const int ch = g * 64 + cl;
    const long long gi = ((long long)(b * C_ + ch)) * N_ + t * 64 + nl0;
    const float4 v = *(const float4*)(x + gi);
    const float gm = gamma[ch], bt = beta[ch];
    short s0 = f2bf((v.x - ms.x) * ms.y * gm + bt);
    short s1 = f2bf((v.y - ms.x) * ms.y * gm + bt);
    short s2 = f2bf((v.z - ms.x) * ms.y * gm + bt);
    short s3 = f2bf((v.w - ms.x) * ms.y * gm + bt);
    short4 pk; pk.x = s0; pk.y = s1; pk.z = s2; pk.w = s3;
    *(short4*)(xnc + gi) = pk;
    tile[cl * 65 + nl0] = s0;
    tile[cl * 65 + nl0 + 1] = s1;
    tile[cl * 65 + nl0 + 2] = s2;
    tile[cl * 65 + nl0 + 3] = s3;
  }
  __syncthreads();

#pragma unroll
  for (int i = 0; i < 4; ++i) {
    const int idx = threadIdx.x + i * 256;
    const int cl0 = (idx & 15) * 4;
    const int nl = idx >> 4;
    short4 pk;
    pk.x = tile[(cl0 + 0) * 65 + nl];
    pk.y = tile[(cl0 + 1) * 65 + nl];
    pk.z = tile[(cl0 + 2) * 65 + nl];
    pk.w = tile[(cl0 + 3) * 65 + nl];
    *(short4*)(xnT + ((long long)b * N_ + t * 64 + nl) * C_ + g * 64 + cl0) = pk;
  }
}

// ---------------- f32 -> bf16 convert
__global__ void conv_bf16_k(const float* __restrict__ src, short* __restrict__ dst, int n) {
  int stride = gridDim.x * blockDim.x;
  for (int i = blockIdx.x * blockDim.x + threadIdx.x; i < n; i += stride)
    dst[i] = f2bf(src[i]);
}

// ---------------- transpose+convert: src [1024][256] f32 -> dst [256][1024] bf16
__global__ __launch_bounds__(256) void tEF(const float* __restrict__ src, short* __restrict__ dst) {
  __shared__ float tl[32 * 33];
  const int bx = blockIdx.x;
  const int by = blockIdx.y;
  const int lx = threadIdx.x & 31, ly = threadIdx.x >> 5;
#pragma unroll
  for (int i = 0; i < 4; ++i) {
    int n = bx * 32 + ly + i * 8;
    int k = by * 32 + lx;
    tl[(ly + i * 8) * 33 + lx] = src[n * 256 + k];
  }
  __syncthreads();
#pragma unroll
  for (int i = 0; i < 4; ++i) {
    int k = by * 32 + ly + i * 8;
    int n = bx * 32 + lx;
    dst[k * 1024 + n] = f2bf(tl[lx * 33 + (ly + i * 8)]);
  }
}

// ---------------- generic GEMM: C[M][Nn] = A (M x Kd, row-major) * Bt (Nn x Kd, row-major)^T
template <int BIAS_MODE, bool OUT_BF16, bool RESID>
__global__ __launch_bounds__(256) void gemm_bt(
    const short* __restrict__ A, const short* __restrict__ Bt,
    void* __restrict__ Cout, const float* __restrict__ bias,
    const short* __restrict__ resid, int M, int Nn, int Kd,
    long long sA, long long sB, long long sC) {
  const int bz = blockIdx.z;
  const int m0 = blockIdx.x * 128;
  const int n0 = blockIdx.y * 128;
  const short* Ab = A + bz * sA;
  const short* Bb = Bt + bz * sB;
  const int tid = threadIdx.x;
  const int lane = tid & 63;
  const int wid = tid >> 6;
  const int wm = wid >> 1, wn = wid & 1;

  __shared__ __align__(16) short As[128 * 64];
  __shared__ __align__(16) short Bs[128 * 64];

  f32x4 acc[4][4] = {};

  for (int kt = 0; kt < Kd; kt += 64) {
#pragma unroll
    for (int r = 0; r < 4; ++r) {
      const int dbase = r * 4096 + wid * 1024;
      const int dbyte = dbase + (lane << 4);
      const int row = dbyte >> 7;
      const int chunk = ((dbyte >> 4) & 7) ^ (row & 7);
      gload16(Ab + (long long)(m0 + row) * Kd + kt + chunk * 8, (char*)As + dbase);
      gload16(Bb + (long long)(n0 + row) * Kd + kt + chunk * 8, (char*)Bs + dbase);
    }
    __syncthreads();
#pragma unroll
    for (int kk = 0; kk < 2; ++kk) {
      bf16x8 af[4], bfr[4];
#pragma unroll
      for (int mi = 0; mi < 4; ++mi) {
        int row = wm * 64 + mi * 16 + (lane & 15);
        int chunk = (kk * 4 + (lane >> 4)) ^ (row & 7);
        af[mi] = *(const bf16x8*)(As + row * 64 + chunk * 8);
      }
#pragma unroll
      for (int ni = 0; ni < 4; ++ni) {
        int row = wn * 64 + ni * 16 + (lane & 15);
        int chunk = (kk * 4 + (lane >> 4)) ^ (row & 7);
        bfr[ni] = *(const bf16x8*)(Bs + row * 64 + chunk * 8);
      }
#pragma unroll
      for (int mi = 0; mi < 4; ++mi)
#pragma unroll
        for (int ni = 0; ni < 4; ++ni)
          acc[mi][ni] = __builtin_amdgcn_mfma_f32_16x16x32_bf16(af[mi], bfr[ni], acc[mi][ni], 0, 0, 0);
    }
    __syncthreads();
  }

#pragma unroll
  for (int mi = 0; mi < 4; ++mi) {
#pragma unroll
    for (int ni = 0; ni < 4; ++ni) {
      const int row = m0 + wm * 64 + mi * 16 + ((lane >> 4) << 2);
      const int col = n0 + wn * 64 + ni * 16 + (lane & 15);
      f32x4 v = acc[mi][ni];
#pragma unroll
      for (int j = 0; j < 4; ++j) {
        float val = v[j];
        if (BIAS_MODE == 1) val += bias[row + j];
        if (BIAS_MODE == 2) val += bias[col];
        long long ci = bz * sC + (long long)(row + j) * Nn + col;
        if (RESID) val += bf2f(resid[ci]);
        if (OUT_BF16)
          ((short*)Cout)[ci] = f2bf(val);
        else
          ((float*)Cout)[ci] = val;
      }
    }
  }
}

// ---------------- fused Linformer attention, 32x32 swapped-QK, in-register softmax
// q: [b][n][512]; kp: [b][256][512]; vp: [b][512][256]; o: [b][n][512]  (all bf16)
// Grid (4,8,16), 512 threads (8 waves). Each wave owns 32 q-rows; K/V tiles staged
// once per block; NO barriers in the k-loop; online softmax; P stays in registers
// via v_cvt_pk_bf16_f32 + v_permlane32_swap_b32.
__global__ __launch_bounds__(512, 4) void attn_fused32(
    const short* __restrict__ q, const short* __restrict__ kp,
    const short* __restrict__ vp, short* __restrict__ o) {
  const int qt = blockIdx.x;
  const int h = blockIdx.y;
  const int b = blockIdx.z;
  const int tid = threadIdx.x;
  const int lane = tid & 63;
  const int wid = tid >> 6;
  const int nlo = lane & 31;   // 32-group lane: q-col / k-row / d-row
  const int hi = lane >> 5;    // half select

  __shared__ __align__(16) short kbuf[256 * 64];   // kp tile [k][d], swizzled
  __shared__ __align__(16) short vbuf[64 * 256];   // vpT tile [d][k], swizzled

  // stage kp tile (32KB): linear LDS dest, inverse-swizzled global source
  {
    const short* base = kp + (long long)b * (KL * C_) + h * DH_;
#pragma unroll
    for (int i = 0; i < 4; ++i) {
      const int dbyte = (i * 512 + tid) * 16;
      const int row = dbyte >> 7;
      const int chunk = ((dbyte >> 4) & 7) ^ (row & 7);
      gload16(base + row * C_ + chunk * 8, (char*)kbuf + dbyte);
    }
  }
  // stage vpT tile (32KB)
  {
    const short* base = vp + ((long long)b * C_ + h * DH_) * KL;
#pragma unroll
    for (int i = 0; i < 4; ++i) {
      const int dbyte = (i * 512 + tid) * 16;
      const int row = dbyte >> 9;
      const int chunk = ((dbyte >> 4) & 31) ^ (row & 7);
      gload16(base + row * KL + chunk * 8, (char*)vbuf + dbyte);
    }
  }

  // Q B-fragments (global, independent of LDS): col n = n0+nlo, k-dim d
  const int n0 = qt * 256 + wid * 32;
  bf16x8 bq[4];
  {
    const short* qb = q + ((long long)b * N_ + n0 + nlo) * C_ + h * DH_ + hi * 8;
#pragma unroll
    for (int dk = 0; dk < 4; ++dk) bq[dk] = *(const bf16x8*)(qb + dk * 16);
  }
  __syncthreads();

  f32x16 oa0, oa1;
#pragma unroll
  for (int r = 0; r < 16; ++r) { oa0[r] = 0.f; oa1[r] = 0.f; }
  float mrun = -1e30f, lrun = 0.f;

#pragma unroll
  for (int kb = 0; kb < 8; ++kb) {
    // S^T[k_local][n] = sum_d K[k][d] * Q[n][d]
    f32x16 s;
#pragma unroll
    for (int r = 0; r < 16; ++r) s[r] = 0.f;
#pragma unroll
    for (int dk = 0; dk < 4; ++dk) {
      const int row = kb * 32 + nlo;
      bf16x8 ak = *(const bf16x8*)(kbuf + row * 64 + (((dk * 2 + hi) ^ (nlo & 7)) * 8));
      s = __builtin_amdgcn_mfma_f32_32x32x16_bf16(ak, bq[dk], s, 0, 0, 0);
    }
    // online softmax: scale, block max, rescale running state
    float lm = -1e30f;
#pragma unroll
    for (int r = 0; r < 16; ++r) { s[r] *= 0.125f; lm = fmaxf(lm, s[r]); }
    lm = fmaxf(lm, __shfl_xor(lm, 32));
    const float mnew = fmaxf(mrun, lm);
    const float sc_old = __expf(mrun - mnew);
    float ls = 0.f;
#pragma unroll
    for (int r = 0; r < 16; ++r) {
      float p = __expf(s[r] - mnew);
      s[r] = p;
      ls += p;
    }
    ls += __shfl_xor(ls, 32);
    lrun = lrun * sc_old + ls;
    mrun = mnew;
#pragma unroll
    for (int r = 0; r < 16; ++r) { oa0[r] *= sc_old; oa1[r] *= sc_old; }

    // pack P^T to bf16 pairs: w[i] = {p[2i] lo, p[2i+1] hi}
    unsigned int w[8];
#pragma unroll
    for (int i = 0; i < 8; ++i) {
      float plo = s[2 * i], phi = s[2 * i + 1];
      unsigned int pk;
      asm("v_cvt_pk_bf16_f32 %0, %1, %2" : "=v"(pk) : "v"(plo), "v"(phi));
      w[i] = pk;
    }
    // PV: two k=16 MFMAs per kb; B-frag assembled via permlane32_swap
#pragma unroll
    for (int m = 0; m < 2; ++m) {
      unsigned int u0 = w[4 * m + 0], u1 = w[4 * m + 1];
      unsigned int u2 = w[4 * m + 2], u3 = w[4 * m + 3];
      // u0 <- [u0.lo | u2.lo] (B word0), u2 <- [u0.hi | u2.hi] (B word2)
      asm volatile("v_permlane32_swap_b32 %0, %1" : "+v"(u0), "+v"(u2));
      asm volatile("v_permlane32_swap_b32 %0, %1" : "+v"(u1), "+v"(u3));
      union { unsigned int u[4]; bf16x8 v; } bp;
      bp.u[0] = u0; bp.u[1] = u1; bp.u[2] = u2; bp.u[3] = u3;
      const int ck = ((kb * 4 + m * 2 + hi) ^ (nlo & 7)) * 8;
      bf16x8 av0 = *(const bf16x8*)(vbuf + (nlo) * 256 + ck);
      bf16x8 av1 = *(const bf16x8*)(vbuf + (32 + nlo) * 256 + ck);
      oa0 = __builtin_amdgcn_mfma_f32_32x32x16_bf16(av0, bp.v, oa0, 0, 0, 0);
      oa1 = __builtin_amdgcn_mfma_f32_32x32x16_bf16(av1, bp.v, oa1, 0, 0, 0);
    }
  }

  // epilogue: O^T[d][n] -> o[b][n][h*64+d], divide by row-sum
  const float rinv = 1.f / lrun;
  short* ob = o + ((long long)b * N_ + n0 + nlo) * C_ + h * DH_;
#pragma unroll
  for (int a = 0; a < 4; ++a) {
    short4 p0, p1;
    p0.x = f2bf(oa0[4 * a + 0] * rinv); p0.y = f2bf(oa0[4 * a + 1] * rinv);
    p0.z = f2bf(oa0[4 * a + 2] * rinv); p0.w = f2bf(oa0[4 * a + 3] * rinv);
    p1.x = f2bf(oa1[4 * a + 0] * rinv); p1.y = f2bf(oa1[4 * a + 1] * rinv);
    p1.z = f2bf(oa1[4 * a + 2] * rinv); p1.w = f2bf(oa1[4 * a + 3] * rinv);
    *(short4*)(ob + a * 8 + hi * 4) = p0;
    *(short4*)(ob + 32 + a * 8 + hi * 4) = p1;
  }
}

extern "C" void kernel_launch(void* const* d_in, const int* in_sizes, int n_in,
                              void* d_out, int out_size, void* d_ws, size_t ws_size,
                              hipStream_t stream) {
  (void)in_sizes; (void)n_in; (void)out_size; (void)ws_size;
  const float* x      = (const float*)d_in[0];
  const float* gamma  = (const float*)d_in[1];
  const float* beta   = (const float*)d_in[2];
  const float* w_qkv  = (const float*)d_in[3];
  const float* b_qkv  = (const float*)d_in[4];
  const float* E      = (const float*)d_in[5];
  const float* F      = (const float*)d_in[6];
  const float* w_o    = (const float*)d_in[7];
  const float* b_o    = (const float*)d_in[8];
  const float* w_proj = (const float*)d_in[9];
  const float* b_proj = (const float*)d_in[10];
  float* out = (float*)d_out;

  char* ws = (char*)d_ws;
  short* xnc    = (short*)ws;  ws += 16777216LL;   // [16][512][1024] bf16 (residual)
  short* xnT    = (short*)ws;  ws += 16777216LL;   // [16][1024][512] bf16 (later: attno)
  short* qbuf   = (short*)ws;  ws += 16777216LL;   // [16][1024][512] bf16
  short* kvbuf  = (short*)ws;  ws += 33554432LL;   // [16][1024][1024] bf16 (later: ybuf)
  short* kpb    = (short*)ws;  ws += 4194304LL;    // [16][256][512] bf16
  short* vpb    = (short*)ws;  ws += 4194304LL;    // [16][512][256] bf16
  short* wqkv_b = (short*)ws;  ws += 1572864LL;    // [1536][512] bf16
  short* wo_b   = (short*)ws;  ws += 524288LL;     // [512][512] bf16
  short* wproj_b= (short*)ws;  ws += 524288LL;     // [512][512] bf16
  short* Et     = (short*)ws;  ws += 524288LL;     // [256][1024] bf16
  short* Ft     = (short*)ws;  ws += 524288LL;     // [256][1024] bf16
  float2* part  = (float2*)ws; ws += 8192LL;       // [1024] partial (sum, sumsq)
  float2* musd  = (float2*)ws; ws += 1024LL;       // [128] (mu, rs)
  short* attno  = xnT;
  short* ybuf   = kvbuf;

  // GroupNorm
  gn_stats1<<<dim3(1024), dim3(256), 0, stream>>>(x, part);
  gn_stats2<<<dim3(1), dim3(128), 0, stream>>>(part, musd);
  gn_apply<<<dim3(16, 8, 16), dim3(256), 0, stream>>>(x, gamma, beta, musd, xnc, xnT);

  // weight prep
  conv_bf16_k<<<dim3(512), dim3(256), 0, stream>>>(w_qkv, wqkv_b, 786432);
  conv_bf16_k<<<dim3(256), dim3(256), 0, stream>>>(w_o, wo_b, 262144);
  conv_bf16_k<<<dim3(256), dim3(256), 0, stream>>>(w_proj, wproj_b, 262144);
  tEF<<<dim3(32, 8), dim3(256), 0, stream>>>(E, Et);
  tEF<<<dim3(32, 8), dim3(256), 0, stream>>>(F, Ft);

  // S1a: q[b][n][o] = xnT[b] * w_q^T + b_qkv[col]
  gemm_bt<2, true, false><<<dim3(8, 4, 16), dim3(256), 0, stream>>>(
      xnT, wqkv_b, qbuf, b_qkv, nullptr, 1024, 512, 512,
      1024LL * 512, 0, 1024LL * 512);
  // S1b: kv[b][o'][n] = w_kv * xnT[b]^T + b_qkv[512+row]
  gemm_bt<1, true, false><<<dim3(8, 8, 16), dim3(256), 0, stream>>>(
      wqkv_b + 512 * 512, xnT, kvbuf, b_qkv + 512, nullptr, 1024, 1024, 512,
      0, 1024LL * 512, 1024LL * 1024);
  // S2a: kp[b][k][c] = Et * k_cn[b]^T
  gemm_bt<0, true, false><<<dim3(2, 4, 16), dim3(256), 0, stream>>>(
      Et, kvbuf, kpb, nullptr, nullptr, 256, 512, 1024,
      0, 1024LL * 1024, 256LL * 512);
  // S2b: vp[b][c][k] = v_cn[b] * Ft^T
  gemm_bt<0, true, false><<<dim3(4, 2, 16), dim3(256), 0, stream>>>(
      kvbuf + 512 * 1024, Ft, vpb, nullptr, nullptr, 512, 256, 1024,
      1024LL * 1024, 0, 512LL * 256);
  // attention (new structure)
  attn_fused32<<<dim3(4, 8, 16), dim3(512), 0, stream>>>(qbuf, kpb, vpb, attno);
  // S4: y[b][n][o] = attno[b] * w_o^T + b_o[col]
  gemm_bt<2, true, false><<<dim3(8, 4, 16), dim3(256), 0, stream>>>(
      attno, wo_b, ybuf, b_o, nullptr, 1024, 512, 512,
      1024LL * 512, 0, 1024LL * 512);
  // S5: out[b][o][n] = w_proj * y[b]^T + b_proj[row] + xnc
  gemm_bt<1, false, true><<<dim3(4, 8, 16), dim3(256), 0, stream>>>(
      wproj_b, ybuf, out, b_proj, xnc, 512, 1024, 512,
      0, 1024LL * 512, 512LL * 1024);
}

// Round 5
// 165.225 us; speedup vs baseline: 1.3762x; 1.0693x over previous
//
#include <hip/hip_runtime.h>
#include <hip/hip_bf16.h>

#define B_ 16
#define C_ 512
#define N_ 1024
#define KL 256
#define HEADS_ 8
#define DH_ 64

typedef __attribute__((ext_vector_type(8))) short bf16x8;
typedef __attribute__((ext_vector_type(4))) float f32x4;
typedef __attribute__((ext_vector_type(16))) float f32x16;

__device__ inline short f2bf(float f) {
  __hip_bfloat16 h = __float2bfloat16(f);
  return *reinterpret_cast<short*>(&h);
}

__device__ inline float bf2f(short s) {
  union { unsigned int u; float f; } c;
  c.u = ((unsigned int)(unsigned short)s) << 16;
  return c.f;
}

__device__ inline void gload16(const void* g, void* l) {
  __builtin_amdgcn_global_load_lds(
      (const __attribute__((address_space(1))) void*)g,
      (__attribute__((address_space(3))) void*)l, 16, 0, 0);
}

// ---------------- GroupNorm stats pass 1: 1024 blocks = (b,g) x 8 slices of 8192 elems
__global__ __launch_bounds__(256) void gn_stats1(const float* __restrict__ x,
                                                 float2* __restrict__ part) {
  const int tid = threadIdx.x;
  const int lane = tid & 63, wid = tid >> 6;
  const float4* b4 = (const float4*)(x + (long long)blockIdx.x * 8192);
  float s = 0.f, sq = 0.f;
#pragma unroll
  for (int j = 0; j < 8; ++j) {
    float4 v = b4[tid + j * 256];
    s += v.x + v.y + v.z + v.w;
    sq += v.x * v.x + v.y * v.y + v.z * v.z + v.w * v.w;
  }
#pragma unroll
  for (int m = 1; m < 64; m <<= 1) {
    s += __shfl_xor(s, m);
    sq += __shfl_xor(sq, m);
  }
  __shared__ float red[8];
  if (lane == 0) { red[wid] = s; red[4 + wid] = sq; }
  __syncthreads();
  if (tid == 0)
    part[blockIdx.x] = make_float2(red[0] + red[1] + red[2] + red[3],
                                   red[4] + red[5] + red[6] + red[7]);
}

// ---------------- GroupNorm stats finalize
__global__ void gn_stats2(const float2* __restrict__ part, float2* __restrict__ musd) {
  const int i = threadIdx.x;
  if (i < 128) {
    float s = 0.f, sq = 0.f;
#pragma unroll
    for (int j = 0; j < 8; ++j) {
      float2 p = part[i * 8 + j];
      s += p.x; sq += p.y;
    }
    const float mu = s * (1.f / 65536.f);
    const float var = sq * (1.f / 65536.f) - mu * mu;
    musd[i] = make_float2(mu, rsqrtf(var + 1e-5f));
  }
}

// ---------------- GroupNorm apply: writes xnc (bf16 [b][c][n]) and xnT (bf16 [b][n][c])
__global__ __launch_bounds__(256) void gn_apply(
    const float* __restrict__ x, const float* __restrict__ gamma,
    const float* __restrict__ beta, const float2* __restrict__ musd,
    short* __restrict__ xnc, short* __restrict__ xnT) {
  const int t = blockIdx.x, g = blockIdx.y, b = blockIdx.z;
  const float2 ms = musd[b * 8 + g];
  __shared__ short tile[64 * 65];

#pragma unroll
  for (int i = 0; i < 4; ++i) {
    const int idx = threadIdx.x + i * 256;
    const int cl = idx >> 4;
    const int nl0 = (idx & 15) * 4;
    const int ch = g * 64 + cl;
    const long long gi = ((long long)(b * C_ + ch)) * N_ + t * 64 + nl0;
    const float4 v = *(const float4*)(x + gi);
    const float gm = gamma[ch], bt = beta[ch];
    short s0 = f2bf((v.x - ms.x) * ms.y * gm + bt);
    short s1 = f2bf((v.y - ms.x) * ms.y * gm + bt);
    short s2 = f2bf((v.z - ms.x) * ms.y * gm + bt);
    short s3 = f2bf((v.w - ms.x) * ms.y * gm + bt);
    short4 pk; pk.x = s0; pk.y = s1; pk.z = s2; pk.w = s3;
    *(short4*)(xnc + gi) = pk;
    tile[cl * 65 + nl0] = s0;
    tile[cl * 65 + nl0 + 1] = s1;
    tile[cl * 65 + nl0 + 2] = s2;
    tile[cl * 65 + nl0 + 3] = s3;
  }
  __syncthreads();

#pragma unroll
  for (int i = 0; i < 4; ++i) {
    const int idx = threadIdx.x + i * 256;
    const int cl0 = (idx & 15) * 4;
    const int nl = idx >> 4;
    short4 pk;
    pk.x = tile[(cl0 + 0) * 65 + nl];
    pk.y = tile[(cl0 + 1) * 65 + nl];
    pk.z = tile[(cl0 + 2) * 65 + nl];
    pk.w = tile[(cl0 + 3) * 65 + nl];
    *(short4*)(xnT + ((long long)b * N_ + t * 64 + nl) * C_ + g * 64 + cl0) = pk;
  }
}

// ---------------- f32 -> bf16 convert
__global__ void conv_bf16_k(const float* __restrict__ src, short* __restrict__ dst, int n) {
  int stride = gridDim.x * blockDim.x;
  for (int i = blockIdx.x * blockDim.x + threadIdx.x; i < n; i += stride)
    dst[i] = f2bf(src[i]);
}

// ---------------- transpose+convert: src [1024][256] f32 -> dst [256][1024] bf16
__global__ __launch_bounds__(256) void tEF(const float* __restrict__ src, short* __restrict__ dst) {
  __shared__ float tl[32 * 33];
  const int bx = blockIdx.x;
  const int by = blockIdx.y;
  const int lx = threadIdx.x & 31, ly = threadIdx.x >> 5;
#pragma unroll
  for (int i = 0; i < 4; ++i) {
    int n = bx * 32 + ly + i * 8;
    int k = by * 32 + lx;
    tl[(ly + i * 8) * 33 + lx] = src[n * 256 + k];
  }
  __syncthreads();
#pragma unroll
  for (int i = 0; i < 4; ++i) {
    int k = by * 32 + ly + i * 8;
    int n = bx * 32 + lx;
    dst[k * 1024 + n] = f2bf(tl[lx * 33 + (ly + i * 8)]);
  }
}

// ---------------- generic GEMM: C[M][Nn] = A (M x Kd, row-major) * Bt (Nn x Kd, row-major)^T
// 2-phase double-buffered K-loop (prefetch overlaps MFMA); bijective XCD chunk
// swizzle on the linearized block id (requires nwg % 8 == 0 — true for all launches).
template <int BIAS_MODE, bool OUT_BF16, bool RESID>
__global__ __launch_bounds__(256) void gemm_bt(
    const short* __restrict__ A, const short* __restrict__ Bt,
    void* __restrict__ Cout, const float* __restrict__ bias,
    const short* __restrict__ resid, int M, int Nn, int Kd,
    long long sA, long long sB, long long sC) {
  // XCD swizzle: physical id -> work id so consecutive work (shared B-panels,
  // then shared A-panels within a batch slab) stays on one XCD's L2.
  const int gx = gridDim.x, gy = gridDim.y;
  const int nwg = gx * gy * gridDim.z;
  const int bid = blockIdx.x + gx * (blockIdx.y + gy * blockIdx.z);
  const int cpx = nwg >> 3;
  int w = (bid & 7) * cpx + (bid >> 3);
  const int mx = w % gx; w /= gx;
  const int ny = w % gy;
  const int bz = w / gy;

  const int m0 = mx * 128;
  const int n0 = ny * 128;
  const short* Ab = A + bz * sA;
  const short* Bb = Bt + bz * sB;
  const int tid = threadIdx.x;
  const int lane = tid & 63;
  const int wid = tid >> 6;
  const int wm = wid >> 1, wn = wid & 1;

  __shared__ __align__(16) short As[2][128 * 64];
  __shared__ __align__(16) short Bs[2][128 * 64];

  auto stage = [&](int bufi, int kt) {
#pragma unroll
    for (int r = 0; r < 4; ++r) {
      const int dbase = r * 4096 + wid * 1024;
      const int dbyte = dbase + (lane << 4);
      const int row = dbyte >> 7;
      const int chunk = ((dbyte >> 4) & 7) ^ (row & 7);
      gload16(Ab + (long long)(m0 + row) * Kd + kt + chunk * 8, (char*)As[bufi] + dbase);
      gload16(Bb + (long long)(n0 + row) * Kd + kt + chunk * 8, (char*)Bs[bufi] + dbase);
    }
  };

  f32x4 acc[4][4] = {};

  stage(0, 0);
  __syncthreads();  // implicit vmcnt(0) drain: buf0 ready

  int cur = 0;
  for (int kt = 0; kt < Kd; kt += 64) {
    if (kt + 64 < Kd) stage(cur ^ 1, kt + 64);  // prefetch flies under MFMAs
#pragma unroll
    for (int kk = 0; kk < 2; ++kk) {
      bf16x8 af[4], bfr[4];
#pragma unroll
      for (int mi = 0; mi < 4; ++mi) {
        int row = wm * 64 + mi * 16 + (lane & 15);
        int chunk = (kk * 4 + (lane >> 4)) ^ (row & 7);
        af[mi] = *(const bf16x8*)(As[cur] + row * 64 + chunk * 8);
      }
#pragma unroll
      for (int ni = 0; ni < 4; ++ni) {
        int row = wn * 64 + ni * 16 + (lane & 15);
        int chunk = (kk * 4 + (lane >> 4)) ^ (row & 7);
        bfr[ni] = *(const bf16x8*)(Bs[cur] + row * 64 + chunk * 8);
      }
#pragma unroll
      for (int mi = 0; mi < 4; ++mi)
#pragma unroll
        for (int ni = 0; ni < 4; ++ni)
          acc[mi][ni] = __builtin_amdgcn_mfma_f32_16x16x32_bf16(af[mi], bfr[ni], acc[mi][ni], 0, 0, 0);
    }
    __syncthreads();  // drains prefetch (vmcnt0) + all waves done reading As[cur]
    cur ^= 1;
  }

#pragma unroll
  for (int mi = 0; mi < 4; ++mi) {
#pragma unroll
    for (int ni = 0; ni < 4; ++ni) {
      const int row = m0 + wm * 64 + mi * 16 + ((lane >> 4) << 2);
      const int col = n0 + wn * 64 + ni * 16 + (lane & 15);
      f32x4 v = acc[mi][ni];
#pragma unroll
      for (int j = 0; j < 4; ++j) {
        float val = v[j];
        if (BIAS_MODE == 1) val += bias[row + j];
        if (BIAS_MODE == 2) val += bias[col];
        long long ci = bz * sC + (long long)(row + j) * Nn + col;
        if (RESID) val += bf2f(resid[ci]);
        if (OUT_BF16)
          ((short*)Cout)[ci] = f2bf(val);
        else
          ((float*)Cout)[ci] = val;
      }
    }
  }
}

// ---------------- fused Linformer attention, 32x32 swapped-QK, in-register softmax
__global__ __launch_bounds__(512, 4) void attn_fused32(
    const short* __restrict__ q, const short* __restrict__ kp,
    const short* __restrict__ vp, short* __restrict__ o) {
  const int qt = blockIdx.x;
  const int h = blockIdx.y;
  const int b = blockIdx.z;
  const int tid = threadIdx.x;
  const int lane = tid & 63;
  const int wid = tid >> 6;
  const int nlo = lane & 31;
  const int hi = lane >> 5;

  __shared__ __align__(16) short kbuf[256 * 64];
  __shared__ __align__(16) short vbuf[64 * 256];

  {
    const short* base = kp + (long long)b * (KL * C_) + h * DH_;
#pragma unroll
    for (int i = 0; i < 4; ++i) {
      const int dbyte = (i * 512 + tid) * 16;
      const int row = dbyte >> 7;
      const int chunk = ((dbyte >> 4) & 7) ^ (row & 7);
      gload16(base + row * C_ + chunk * 8, (char*)kbuf + dbyte);
    }
  }
  {
    const short* base = vp + ((long long)b * C_ + h * DH_) * KL;
#pragma unroll
    for (int i = 0; i < 4; ++i) {
      const int dbyte = (i * 512 + tid) * 16;
      const int row = dbyte >> 9;
      const int chunk = ((dbyte >> 4) & 31) ^ (row & 7);
      gload16(base + row * KL + chunk * 8, (char*)vbuf + dbyte);
    }
  }

  const int n0 = qt * 256 + wid * 32;
  bf16x8 bq[4];
  {
    const short* qb = q + ((long long)b * N_ + n0 + nlo) * C_ + h * DH_ + hi * 8;
#pragma unroll
    for (int dk = 0; dk < 4; ++dk) bq[dk] = *(const bf16x8*)(qb + dk * 16);
  }
  __syncthreads();

  f32x16 oa0, oa1;
#pragma unroll
  for (int r = 0; r < 16; ++r) { oa0[r] = 0.f; oa1[r] = 0.f; }
  float mrun = -1e30f, lrun = 0.f;

#pragma unroll
  for (int kb = 0; kb < 8; ++kb) {
    f32x16 s;
#pragma unroll
    for (int r = 0; r < 16; ++r) s[r] = 0.f;
#pragma unroll
    for (int dk = 0; dk < 4; ++dk) {
      const int row = kb * 32 + nlo;
      bf16x8 ak = *(const bf16x8*)(kbuf + row * 64 + (((dk * 2 + hi) ^ (nlo & 7)) * 8));
      s = __builtin_amdgcn_mfma_f32_32x32x16_bf16(ak, bq[dk], s, 0, 0, 0);
    }
    float lm = -1e30f;
#pragma unroll
    for (int r = 0; r < 16; ++r) { s[r] *= 0.125f; lm = fmaxf(lm, s[r]); }
    lm = fmaxf(lm, __shfl_xor(lm, 32));
    const float mnew = fmaxf(mrun, lm);
    const float sc_old = __expf(mrun - mnew);
    float ls = 0.f;
#pragma unroll
    for (int r = 0; r < 16; ++r) {
      float p = __expf(s[r] - mnew);
      s[r] = p;
      ls += p;
    }
    ls += __shfl_xor(ls, 32);
    lrun = lrun * sc_old + ls;
    mrun = mnew;
#pragma unroll
    for (int r = 0; r < 16; ++r) { oa0[r] *= sc_old; oa1[r] *= sc_old; }

    unsigned int w[8];
#pragma unroll
    for (int i = 0; i < 8; ++i) {
      float plo = s[2 * i], phi = s[2 * i + 1];
      unsigned int pk;
      asm("v_cvt_pk_bf16_f32 %0, %1, %2" : "=v"(pk) : "v"(plo), "v"(phi));
      w[i] = pk;
    }
#pragma unroll
    for (int m = 0; m < 2; ++m) {
      unsigned int u0 = w[4 * m + 0], u1 = w[4 * m + 1];
      unsigned int u2 = w[4 * m + 2], u3 = w[4 * m + 3];
      asm volatile("v_permlane32_swap_b32 %0, %1" : "+v"(u0), "+v"(u2));
      asm volatile("v_permlane32_swap_b32 %0, %1" : "+v"(u1), "+v"(u3));
      union { unsigned int u[4]; bf16x8 v; } bp;
      bp.u[0] = u0; bp.u[1] = u1; bp.u[2] = u2; bp.u[3] = u3;
      const int ck = ((kb * 4 + m * 2 + hi) ^ (nlo & 7)) * 8;
      bf16x8 av0 = *(const bf16x8*)(vbuf + (nlo) * 256 + ck);
      bf16x8 av1 = *(const bf16x8*)(vbuf + (32 + nlo) * 256 + ck);
      oa0 = __builtin_amdgcn_mfma_f32_32x32x16_bf16(av0, bp.v, oa0, 0, 0, 0);
      oa1 = __builtin_amdgcn_mfma_f32_32x32x16_bf16(av1, bp.v, oa1, 0, 0, 0);
    }
  }

  const float rinv = 1.f / lrun;
  short* ob = o + ((long long)b * N_ + n0 + nlo) * C_ + h * DH_;
#pragma unroll
  for (int a = 0; a < 4; ++a) {
    short4 p0, p1;
    p0.x = f2bf(oa0[4 * a + 0] * rinv); p0.y = f2bf(oa0[4 * a + 1] * rinv);
    p0.z = f2bf(oa0[4 * a + 2] * rinv); p0.w = f2bf(oa0[4 * a + 3] * rinv);
    p1.x = f2bf(oa1[4 * a + 0] * rinv); p1.y = f2bf(oa1[4 * a + 1] * rinv);
    p1.z = f2bf(oa1[4 * a + 2] * rinv); p1.w = f2bf(oa1[4 * a + 3] * rinv);
    *(short4*)(ob + a * 8 + hi * 4) = p0;
    *(short4*)(ob + 32 + a * 8 + hi * 4) = p1;
  }
}

extern "C" void kernel_launch(void* const* d_in, const int* in_sizes, int n_in,
                              void* d_out, int out_size, void* d_ws, size_t ws_size,
                              hipStream_t stream) {
  (void)in_sizes; (void)n_in; (void)out_size; (void)ws_size;
  const float* x      = (const float*)d_in[0];
  const float* gamma  = (const float*)d_in[1];
  const float* beta   = (const float*)d_in[2];
  const float* w_qkv  = (const float*)d_in[3];
  const float* b_qkv  = (const float*)d_in[4];
  const float* E      = (const float*)d_in[5];
  const float* F      = (const float*)d_in[6];
  const float* w_o    = (const float*)d_in[7];
  const float* b_o    = (const float*)d_in[8];
  const float* w_proj = (const float*)d_in[9];
  const float* b_proj = (const float*)d_in[10];
  float* out = (float*)d_out;

  char* ws = (char*)d_ws;
  short* xnc    = (short*)ws;  ws += 16777216LL;   // [16][512][1024] bf16 (residual)
  short* xnT    = (short*)ws;  ws += 16777216LL;   // [16][1024][512] bf16 (later: attno)
  short* qbuf   = (short*)ws;  ws += 16777216LL;   // [16][1024][512] bf16
  short* kvbuf  = (short*)ws;  ws += 33554432LL;   // [16][1024][1024] bf16 (later: ybuf)
  short* kpb    = (short*)ws;  ws += 4194304LL;    // [16][256][512] bf16
  short* vpb    = (short*)ws;  ws += 4194304LL;    // [16][512][256] bf16
  short* wqkv_b = (short*)ws;  ws += 1572864LL;    // [1536][512] bf16
  short* wo_b   = (short*)ws;  ws += 524288LL;     // [512][512] bf16
  short* wproj_b= (short*)ws;  ws += 524288LL;     // [512][512] bf16
  short* Et     = (short*)ws;  ws += 524288LL;     // [256][1024] bf16
  short* Ft     = (short*)ws;  ws += 524288LL;     // [256][1024] bf16
  float2* part  = (float2*)ws; ws += 8192LL;       // [1024] partial (sum, sumsq)
  float2* musd  = (float2*)ws; ws += 1024LL;       // [128] (mu, rs)
  short* attno  = xnT;
  short* ybuf   = kvbuf;

  // GroupNorm
  gn_stats1<<<dim3(1024), dim3(256), 0, stream>>>(x, part);
  gn_stats2<<<dim3(1), dim3(128), 0, stream>>>(part, musd);
  gn_apply<<<dim3(16, 8, 16), dim3(256), 0, stream>>>(x, gamma, beta, musd, xnc, xnT);

  // weight prep
  conv_bf16_k<<<dim3(512), dim3(256), 0, stream>>>(w_qkv, wqkv_b, 786432);
  conv_bf16_k<<<dim3(256), dim3(256), 0, stream>>>(w_o, wo_b, 262144);
  conv_bf16_k<<<dim3(256), dim3(256), 0, stream>>>(w_proj, wproj_b, 262144);
  tEF<<<dim3(32, 8), dim3(256), 0, stream>>>(E, Et);
  tEF<<<dim3(32, 8), dim3(256), 0, stream>>>(F, Ft);

  // S1a: q[b][n][o] = xnT[b] * w_q^T + b_qkv[col]
  gemm_bt<2, true, false><<<dim3(8, 4, 16), dim3(256), 0, stream>>>(
      xnT, wqkv_b, qbuf, b_qkv, nullptr, 1024, 512, 512,
      1024LL * 512, 0, 1024LL * 512);
  // S1b: kv[b][o'][n] = w_kv * xnT[b]^T + b_qkv[512+row]
  gemm_bt<1, true, false><<<dim3(8, 8, 16), dim3(256), 0, stream>>>(
      wqkv_b + 512 * 512, xnT, kvbuf, b_qkv + 512, nullptr, 1024, 1024, 512,
      0, 1024LL * 512, 1024LL * 1024);
  // S2a: kp[b][k][c] = Et * k_cn[b]^T
  gemm_bt<0, true, false><<<dim3(2, 4, 16), dim3(256), 0, stream>>>(
      Et, kvbuf, kpb, nullptr, nullptr, 256, 512, 1024,
      0, 1024LL * 1024, 256LL * 512);
  // S2b: vp[b][c][k] = v_cn[b] * Ft^T
  gemm_bt<0, true, false><<<dim3(4, 2, 16), dim3(256), 0, stream>>>(
      kvbuf + 512 * 1024, Ft, vpb, nullptr, nullptr, 512, 256, 1024,
      1024LL * 1024, 0, 512LL * 256);
  // attention
  attn_fused32<<<dim3(4, 8, 16), dim3(512), 0, stream>>>(qbuf, kpb, vpb, attno);
  // S4: y[b][n][o] = attno[b] * w_o^T + b_o[col]
  gemm_bt<2, true, false><<<dim3(8, 4, 16), dim3(256), 0, stream>>>(
      attno, wo_b, ybuf, b_o, nullptr, 1024, 512, 512,
      1024LL * 512, 0, 1024LL * 512);
  // S5: out[b][o][n] = w_proj * y[b]^T + b_proj[row] + xnc
  gemm_bt<1, false, true><<<dim3(4, 8, 16), dim3(256), 0, stream>>>(
      wproj_b, ybuf, out, b_proj, xnc, 512, 1024, 512,
      0, 1024LL * 512, 512LL * 1024);
}